// Round 17
// baseline (265.669 us; speedup 1.0000x reference)
//
#include <hip/hip_runtime.h>

#define DD   32
#define BKT  128      // dsts per bucket (power of two)
#define BSH  7        // log2(BKT)
#define CAP  1536     // fixed slots per bucket (mean fill 1280, max ~1405)
#define PCH  2048     // edges per partition block
#define MAXB 2048     // padded bucket-count (>= nbkt)
#define WSET_SH 2112  // ushorts per weight set: 2048 B-frags + 64 (32 f32 bias)
#define CB   1024     // cast blocks inside k_mega

typedef __attribute__((ext_vector_type(8))) short short8v;   // 8 bf16 (4 VGPR)
typedef __attribute__((ext_vector_type(4))) float float4v;   // mfma C/D

// ---------- f32 -> bf16 (RNE) helpers ----------------------------------------
__device__ __forceinline__ unsigned bfr(float f) {
    unsigned u = __float_as_uint(f);
    return (u + 0x7fffu + ((u >> 16) & 1u)) >> 16;
}
__device__ __forceinline__ unsigned pk2(float a, float b) {
    return bfr(a) | (bfr(b) << 16);
}

// ---------- mega preamble: wprep | x->bf16 cast | bucket partition -----------
// Block roles by range: [0,4) wprep, [4,4+CB) cast, [4+CB, 4+CB+2*EB) part.
// Partition LDS compressed to ~25 KB: packed-ushort histogram (atomic add of
// 1<<((bk&1)*16); counts <= PCH=2048 so halves can't overflow), ushort
// basev/gb. 6 blocks/CU vs R16's 3.
__global__ __launch_bounds__(256) void k_mega(
        const float* W0s, const float* W0n, const float* b0,
        const float* W1s, const float* W1n, const float* b1,
        const float* W2s, const float* W2n, const float* b2,
        const float* W3s, const float* W3n, const float* b3,
        unsigned short* __restrict__ wout,
        const float* __restrict__ xU, uint4* __restrict__ xbU, int n4U,
        const float* __restrict__ xI, uint4* __restrict__ xbI, int n4I,
        const int* __restrict__ srcA, const int* __restrict__ dstA,
        int* __restrict__ curA, int* __restrict__ stA,
        const int* __restrict__ srcB, const int* __restrict__ dstB,
        int* __restrict__ curB, int* __restrict__ stB,
        int E, int EB) {
    __shared__ int pk[PCH];                    // 8 KB
    __shared__ unsigned short bkl[PCH];        // 4 KB
    __shared__ int histP[MAXB / 2];            // 4 KB packed 2xushort
    __shared__ unsigned short bv[MAXB];        // 4 KB
    __shared__ unsigned short gb[MAXB];        // 4 KB
    __shared__ int red[256];                   // 1 KB
    int b = blockIdx.x;
    int t = threadIdx.x;
    if (b < 4) {                       // ---- weight prep: pack B fragments ----
        // B-frag for mfma_f32_16x16x32_bf16: lane l, reg i -> B[k][n],
        // n=(l&15)+nt*16, k=(l>>4)*8+i; B[k][n]=W[n][k]
        const float* Ws = (b == 0) ? W0s : (b == 1) ? W1s : (b == 2) ? W2s : W3s;
        const float* Wn = (b == 0) ? W0n : (b == 1) ? W1n : (b == 2) ? W2n : W3n;
        const float* bb = (b == 0) ? b0  : (b == 1) ? b1  : (b == 2) ? b2  : b3;
        unsigned short* o = wout + (size_t)b * WSET_SH;
        int pnt = t >> 6;              // 0:Ws-t0 1:Ws-t1 2:Wn-t0 3:Wn-t1
        int l   = t & 63;
        const float* W = (pnt < 2) ? Ws : Wn;
        int nt  = pnt & 1;
        int col = nt * 16 + (l & 15);
        int k0  = (l >> 4) * 8;
        unsigned short v[8];
#pragma unroll
        for (int i = 0; i < 8; ++i) v[i] = (unsigned short)bfr(W[col * DD + k0 + i]);
        uint4 pkv;
        pkv.x = v[0] | ((unsigned)v[1] << 16);
        pkv.y = v[2] | ((unsigned)v[3] << 16);
        pkv.z = v[4] | ((unsigned)v[5] << 16);
        pkv.w = v[6] | ((unsigned)v[7] << 16);
        *(uint4*)(o + (size_t)pnt * 512 + (size_t)l * 8) = pkv;
        if (t < DD) ((float*)(o + 2048))[t] = bb[t];
    } else if (b < 4 + CB) {           // ---- x -> bf16 cast ----
        int vb = b - 4;
        int total = n4U + n4I;
        for (int i = vb * 256 + t; i < total; i += CB * 256) {
            const float* s; uint4* dd; int j;
            if (i < n4U) { s = xU; dd = xbU; j = i; }
            else         { s = xI; dd = xbI; j = i - n4U; }
            float4 f0 = ((const float4*)s)[2 * j];
            float4 f1 = ((const float4*)s)[2 * j + 1];
            uint4 o;
            o.x = pk2(f0.x, f0.y); o.y = pk2(f0.z, f0.w);
            o.z = pk2(f1.x, f1.y); o.w = pk2(f1.z, f1.w);
            dd[j] = o;
        }
    } else {                           // ---- bucket partition ----
        int vb = b - 4 - CB;
        const int* src; const int* dst; int* cur; int* st; int bb;
        if (vb < EB) { src = srcA; dst = dstA; cur = curA; st = stA; bb = vb; }
        else         { src = srcB; dst = dstB; cur = curB; st = stB; bb = vb - EB; }
        int lo = bb * PCH;
        int cntE = E - lo; if (cntE > PCH) cntE = PCH;

        for (int i = t; i < MAXB / 2; i += 256) histP[i] = 0;
        __syncthreads();
        for (int k = 0; k < PCH / 256; ++k) {
            int i = t + k * 256;
            if (i < cntE) {
                int bk = dst[lo + i] >> BSH;
                atomicAdd(&histP[bk >> 1], 1u << ((bk & 1) * 16));
            }
        }
        __syncthreads();
        {   // exclusive scan of 2048 bucket counts (8 per thread)
            int base = t * 8;
            int loc[8]; int tot = 0;
            for (int j = 0; j < 8; ++j) {
                int bk = base + j;
                loc[j] = (histP[bk >> 1] >> ((bk & 1) * 16)) & 0xFFFF;
                tot += loc[j];
            }
            red[t] = tot;
            __syncthreads();
            for (int off = 1; off < 256; off <<= 1) {
                int v = (t >= off) ? red[t - off] : 0;
                __syncthreads();
                red[t] += v;
                __syncthreads();
            }
            int run = red[t] - tot;
            for (int j = 0; j < 8; ++j) { bv[base + j] = (unsigned short)run; run += loc[j]; }
        }
        __syncthreads();
        for (int i = t; i < MAXB / 2; i += 256) histP[i] = 0;   // reuse as bump
        __syncthreads();
        for (int k = 0; k < PCH / 256; ++k) {
            int i = t + k * 256;
            if (i < cntE) {
                int s = src[lo + i], d = dst[lo + i];
                int bk = d >> BSH;
                unsigned old = atomicAdd(&histP[bk >> 1], 1u << ((bk & 1) * 16));
                int pos = bv[bk] + ((old >> ((bk & 1) * 16)) & 0xFFFF);
                pk[pos]  = (s << BSH) | (d & (BKT - 1));
                bkl[pos] = (unsigned short)bk;
            }
        }
        __syncthreads();
        for (int i = t; i < MAXB; i += 256) {
            int c = (histP[i >> 1] >> ((i & 1) * 16)) & 0xFFFF;
            gb[i] = (unsigned short)(c ? atomicAdd(&cur[i], c) : 0);
        }
        __syncthreads();
        for (int i = t; i < cntE; i += 256) {
            int bk = bkl[i];
            st[(size_t)bk * CAP + gb[bk] + (i - bv[bk])] = pk[i];
        }
    }
}

// ---------- in-bucket sort + 129-stride rowptr -------------------------------
__global__ __launch_bounds__(256) void k_bsort2(
        const int* __restrict__ curA, int* __restrict__ csrA, int* __restrict__ rpxA, int nbA,
        const int* __restrict__ curB, int* __restrict__ csrB, int* __restrict__ rpxB) {
    __shared__ int buf[CAP];
    __shared__ int hist[BKT];
    __shared__ int sc[BKT];
    __shared__ int cur[BKT];
    int b = blockIdx.x;
    const int* cc; int* csr; int* rpx; int bb;
    if (b < nbA) { cc = curA; csr = csrA; rpx = rpxA; bb = b; }
    else         { cc = curB; csr = csrB; rpx = rpxB; bb = b - nbA; }
    int t = threadIdx.x;
    int s0 = bb * CAP;
    int cnt = cc[bb];
    for (int i = t; i < cnt; i += 256) buf[i] = csr[s0 + i];
    if (t < BKT) hist[t] = 0;
    __syncthreads();
    for (int i = t; i < cnt; i += 256) atomicAdd(&hist[buf[i] & (BKT - 1)], 1);
    __syncthreads();
    int val = (t < BKT) ? hist[t] : 0;
    if (t < BKT) sc[t] = val;
    __syncthreads();
    for (int off = 1; off < BKT; off <<= 1) {
        int u = (t < BKT && t >= off) ? sc[t - off] : 0;
        __syncthreads();
        if (t < BKT) sc[t] += u;
        __syncthreads();
    }
    if (t < BKT) {
        int excl = sc[t] - val;
        cur[t] = excl;
        rpx[bb * (BKT + 1) + t] = s0 + excl;
    }
    if (t == BKT) rpx[bb * (BKT + 1) + BKT] = s0 + cnt;
    __syncthreads();
    for (int i = t; i < cnt; i += 256) {
        int p = buf[i];
        int pos = atomicAdd(&cur[p & (BKT - 1)], 1);
        csr[s0 + pos] = p >> BSH;
    }
}

// ---------- h f32 -> bf16 cast (fallback path only) ---------------------------
__global__ __launch_bounds__(256) void k_cast2(
        const float* __restrict__ sA, uint4* __restrict__ dA, int nA,
        const float* __restrict__ sB, uint4* __restrict__ dB, int nB) {
    int total = nA + nB;
    for (int i = blockIdx.x * 256 + threadIdx.x; i < total; i += gridDim.x * 256) {
        const float* s; uint4* dd; int j;
        if (i < nA) { s = sA; dd = dA; j = i; }
        else        { s = sB; dd = dB; j = i - nA; }
        float4 f0 = ((const float4*)s)[2 * j];
        float4 f1 = ((const float4*)s)[2 * j + 1];
        uint4 o;
        o.x = pk2(f0.x, f0.y); o.y = pk2(f0.z, f0.w);
        o.z = pk2(f1.x, f1.y); o.w = pk2(f1.z, f1.w);
        dd[j] = o;
    }
}

// ---------- quad reduce via DPP (xor1 then xor2, pure VALU) -------------------
__device__ __forceinline__ float qred(float x) {
    x += __int_as_float(__builtin_amdgcn_update_dpp(
            0, __float_as_int(x), 0xB1, 0xF, 0xF, true));
    x += __int_as_float(__builtin_amdgcn_update_dpp(
            0, __float_as_int(x), 0x4E, 0xF, 0xF, true));
    return x;
}

// ---------- fused: gather(bf16) + MFMA transform ------------------------------
__device__ __forceinline__ void fused_body(
        const uint4* __restrict__ gsrc, const unsigned short* __restrict__ xdb,
        const int* __restrict__ rpx, const int* __restrict__ csr_src,
        const unsigned short* __restrict__ wset,
        float* __restrict__ out, unsigned short* __restrict__ outbf,
        int n, int do_relu, int bb) {
    __shared__ unsigned short xm[64][72];
    int tid = threadIdx.x;
    int grp = tid >> 4;
    int ln  = tid & 15;
    int el  = ln & 3;
    int q   = ln >> 2;
    int l64 = tid & 63;
    int w   = tid >> 6;

    const short8v* wb = (const short8v*)wset;
    short8v Bs0 = wb[0 * 64 + l64];
    short8v Bs1 = wb[1 * 64 + l64];
    short8v Bn0 = wb[2 * 64 + l64];
    short8v Bn1 = wb[3 * 64 + l64];
    const float* bias = (const float*)(wset + 2048);
    float bv0 = bias[l64 & 15];
    float bv1 = bias[16 + (l64 & 15)];

#pragma unroll 2
    for (int nn = 0; nn < 4; ++nn) {
        int nl = grp * 4 + nn;
        int v  = bb * 64 + nl;
        if (v < n) {
            ((unsigned*)xm[nl])[ln] = ((const unsigned*)xdb)[(unsigned)v * 16u + ln];
            int rb = (v >> BSH) * (BKT + 1) + (v & (BKT - 1));
            int rs = rpx[rb], re = rpx[rb + 1];
            float a0 = 0.f, a1 = 0.f, a2 = 0.f, a3 = 0.f;
            float a4 = 0.f, a5 = 0.f, a6 = 0.f, a7 = 0.f;
            for (int j0 = rs; j0 < re; j0 += 16) {
                int nj = re - j0; if (nj > 16) nj = 16;
                int myi = (ln < nj) ? csr_src[j0 + ln] : 0;
                for (int c0 = 0; c0 < nj; c0 += 8) {
                    int jj0 = c0 + el;
                    int jj1 = c0 + 4 + el;
                    int s0 = __shfl(myi, jj0, 16);
                    int s1 = __shfl(myi, jj1, 16);
                    if (jj0 < nj) {
                        uint4 w4 = gsrc[(unsigned)s0 * 4u + q];
                        a0 += __uint_as_float(w4.x << 16); a1 += __uint_as_float(w4.x & 0xFFFF0000u);
                        a2 += __uint_as_float(w4.y << 16); a3 += __uint_as_float(w4.y & 0xFFFF0000u);
                        a4 += __uint_as_float(w4.z << 16); a5 += __uint_as_float(w4.z & 0xFFFF0000u);
                        a6 += __uint_as_float(w4.w << 16); a7 += __uint_as_float(w4.w & 0xFFFF0000u);
                    }
                    if (jj1 < nj) {
                        uint4 w4 = gsrc[(unsigned)s1 * 4u + q];
                        a0 += __uint_as_float(w4.x << 16); a1 += __uint_as_float(w4.x & 0xFFFF0000u);
                        a2 += __uint_as_float(w4.y << 16); a3 += __uint_as_float(w4.y & 0xFFFF0000u);
                        a4 += __uint_as_float(w4.z << 16); a5 += __uint_as_float(w4.z & 0xFFFF0000u);
                        a6 += __uint_as_float(w4.w << 16); a7 += __uint_as_float(w4.w & 0xFFFF0000u);
                    }
                }
            }
            a0 = qred(a0); a1 = qred(a1); a2 = qred(a2); a3 = qred(a3);
            a4 = qred(a4); a5 = qred(a5); a6 = qred(a6); a7 = qred(a7);
            float rinv = 1.0f / fmaxf((float)(re - rs), 1.0f);
            if (el == 0) {
                uint4 m4;
                m4.x = pk2(a0 * rinv, a1 * rinv);
                m4.y = pk2(a2 * rinv, a3 * rinv);
                m4.z = pk2(a4 * rinv, a5 * rinv);
                m4.w = pk2(a6 * rinv, a7 * rinv);
                *(uint4*)(&xm[nl][32 + q * 8]) = m4;
            }
        } else {
            ((unsigned*)xm[nl])[ln] = 0;
            if (el == 0) {
                uint4 z; z.x = z.y = z.z = z.w = 0;
                *(uint4*)(&xm[nl][32 + q * 8]) = z;
            }
        }
    }
    __syncthreads();

    int row16 = l64 & 15;
    int kg    = l64 >> 4;
    int nrow  = w * 16 + row16;
    short8v Ax = *(const short8v*)(&xm[nrow][kg * 8]);
    short8v Am = *(const short8v*)(&xm[nrow][32 + kg * 8]);
    float4v c0 = {0.f, 0.f, 0.f, 0.f};
    float4v c1 = {0.f, 0.f, 0.f, 0.f};
    c0 = __builtin_amdgcn_mfma_f32_16x16x32_bf16(Ax, Bs0, c0, 0, 0, 0);
    c0 = __builtin_amdgcn_mfma_f32_16x16x32_bf16(Am, Bn0, c0, 0, 0, 0);
    c1 = __builtin_amdgcn_mfma_f32_16x16x32_bf16(Ax, Bs1, c1, 0, 0, 0);
    c1 = __builtin_amdgcn_mfma_f32_16x16x32_bf16(Am, Bn1, c1, 0, 0, 0);
    int ccol  = l64 & 15;
    int crow0 = (l64 >> 4) * 4;
#pragma unroll
    for (int j = 0; j < 4; ++j) {
        int r = w * 16 + crow0 + j;
        int v = bb * 64 + r;
        if (v < n) {
            float s0v = c0[j] + bv0;
            float s1v = c1[j] + bv1;
            if (do_relu) { s0v = fmaxf(s0v, 0.f); s1v = fmaxf(s1v, 0.f); }
            if (out) {
                out[(unsigned)v * DD + ccol]      = s0v;
                out[(unsigned)v * DD + 16 + ccol] = s1v;
            }
            if (outbf) {
                outbf[(unsigned)v * DD + ccol]      = (unsigned short)bfr(s0v);
                outbf[(unsigned)v * DD + 16 + ccol] = (unsigned short)bfr(s1v);
            }
        }
    }
}

__global__ __launch_bounds__(256) void k_fused2(
        const uint4* gA, const unsigned short* xdA, const int* rpA, const int* csrA,
        const unsigned short* wsetA, float* outA, unsigned short* obfA, int nA, int blocksA,
        const uint4* gB, const unsigned short* xdB, const int* rpB, const int* csrB,
        const unsigned short* wsetB, float* outB, unsigned short* obfB, int nB, int do_relu) {
    int b = blockIdx.x;
    bool A = b < blocksA;
    fused_body(A ? gA : gB, A ? xdA : xdB, A ? rpA : rpB, A ? csrA : csrB,
               A ? wsetA : wsetB, A ? outA : outB, A ? obfA : obfB,
               A ? nA : nB, do_relu, A ? b : b - blocksA);
}

extern "C" void kernel_launch(void* const* d_in, const int* in_sizes, int n_in,
                              void* d_out, int out_size, void* d_ws, size_t ws_size,
                              hipStream_t stream) {
    const float* x_user = (const float*)d_in[0];
    const float* x_item = (const float*)d_in[1];
    const int*   ui_src = (const int*)d_in[2];
    const int*   ui_dst = (const int*)d_in[3];
    const int*   iu_src = (const int*)d_in[4];
    const int*   iu_dst = (const int*)d_in[5];
    const float* Ws_ui1 = (const float*)d_in[6];
    const float* Wn_ui1 = (const float*)d_in[7];
    const float* Ws_iu1 = (const float*)d_in[8];
    const float* Wn_iu1 = (const float*)d_in[9];
    const float* Ws_ui2 = (const float*)d_in[10];
    const float* Wn_ui2 = (const float*)d_in[11];
    const float* Ws_iu2 = (const float*)d_in[12];
    const float* Wn_iu2 = (const float*)d_in[13];
    const float* b_ui1  = (const float*)d_in[14];
    const float* b_iu1  = (const float*)d_in[15];
    const float* b_ui2  = (const float*)d_in[16];
    const float* b_iu2  = (const float*)d_in[17];

    int NU = in_sizes[0] / DD;
    int NI = in_sizes[1] / DD;
    int E  = in_sizes[2];
    int NBI = (NI + BKT - 1) >> BSH;
    int NBU = (NU + BKT - 1) >> BSH;

    // ---- workspace sizing ----
    size_t base_need = (size_t)(NU + NI) * 64
                     + (size_t)(NBI + NBU) * CAP * 4
                     + (size_t)(NBI + NBU) * (BKT + 1) * 4
                     + (size_t)4 * WSET_SH * 2
                     + (size_t)2 * MAXB * 4 + 512;
    size_t hb_extra = (size_t)(NU + NI) * 64;
    bool path1 = (ws_size >= base_need + hb_extra);

    char* wp = (char*)d_ws;
    uint4* xbU = (uint4*)wp;     wp += (size_t)NU * 64;
    uint4* xbI = (uint4*)wp;     wp += (size_t)NI * 64;
    uint4* hbU = xbU;
    uint4* hbI = xbI;
    if (path1) {
        hbU = (uint4*)wp;        wp += (size_t)NU * 64;
        hbI = (uint4*)wp;        wp += (size_t)NI * 64;
    }
    int* csr_ui = (int*)wp;      wp += (size_t)NBI * CAP * 4;
    int* csr_iu = (int*)wp;      wp += (size_t)NBU * CAP * 4;
    int* rpxI   = (int*)wp;      wp += (size_t)NBI * (BKT + 1) * 4;
    int* rpxU   = (int*)wp;      wp += (size_t)NBU * (BKT + 1) * 4;
    wp = (char*)(((size_t)wp + 15) & ~(size_t)15);
    unsigned short* wprep = (unsigned short*)wp;  wp += (size_t)4 * WSET_SH * 2;
    int* curI = (int*)wp;        wp += (size_t)MAXB * 4;
    int* curU = (int*)wp;

    float* h_user = (float*)d_out;
    float* h_item = h_user + (size_t)NU * DD;

    int EB = (E + PCH - 1) / PCH;

    // ---- zero cursors, then mega preamble (wprep | cast | partition) ----
    (void)hipMemsetAsync(curI, 0, (size_t)2 * MAXB * sizeof(int), stream);
    hipLaunchKernelGGL(k_mega, dim3(4 + CB + 2 * EB), dim3(256), 0, stream,
                       Ws_ui1, Wn_ui1, b_ui1, Ws_iu1, Wn_iu1, b_iu1,
                       Ws_ui2, Wn_ui2, b_ui2, Ws_iu2, Wn_iu2, b_iu2, wprep,
                       x_user, xbU, NU * 4, x_item, xbI, NI * 4,
                       ui_src, ui_dst, curI, csr_ui,
                       iu_src, iu_dst, curU, csr_iu, E, EB);

    // ---- in-bucket sort + rowptr ----
    hipLaunchKernelGGL(k_bsort2, dim3(NBI + NBU), dim3(256), 0, stream,
                       curI, csr_ui, rpxI, NBI,
                       curU, csr_iu, rpxU);

    int NBIb = (NI + 63) / 64, NBUb = (NU + 63) / 64;

    if (path1) {
        // L1: gather x-bf16, write h bf16 only
        hipLaunchKernelGGL(k_fused2, dim3(NBIb + NBUb), dim3(256), 0, stream,
                           xbU, (const unsigned short*)xbI, rpxI, csr_ui,
                           wprep + 0 * WSET_SH, (float*)nullptr, (unsigned short*)hbI, NI, NBIb,
                           xbI, (const unsigned short*)xbU, rpxU, csr_iu,
                           wprep + 1 * WSET_SH, (float*)nullptr, (unsigned short*)hbU, NU, 1);
        // L2: gather h-bf16, write f32 outputs to d_out
        hipLaunchKernelGGL(k_fused2, dim3(NBIb + NBUb), dim3(256), 0, stream,
                           hbU, (const unsigned short*)hbI, rpxI, csr_ui,
                           wprep + 2 * WSET_SH, h_item, (unsigned short*)nullptr, NI, NBIb,
                           hbI, (const unsigned short*)hbU, rpxU, csr_iu,
                           wprep + 3 * WSET_SH, h_user, (unsigned short*)nullptr, NU, 0);
    } else {
        hipLaunchKernelGGL(k_fused2, dim3(NBIb + NBUb), dim3(256), 0, stream,
                           xbU, (const unsigned short*)xbI, rpxI, csr_ui,
                           wprep + 0 * WSET_SH, h_item, (unsigned short*)nullptr, NI, NBIb,
                           xbI, (const unsigned short*)xbU, rpxU, csr_iu,
                           wprep + 1 * WSET_SH, h_user, (unsigned short*)nullptr, NU, 1);
        hipLaunchKernelGGL(k_cast2, dim3(1024), dim3(256), 0, stream,
                           h_user, xbU, NU * 4, h_item, xbI, NI * 4);
        hipLaunchKernelGGL(k_fused2, dim3(NBIb + NBUb), dim3(256), 0, stream,
                           xbU, (const unsigned short*)xbI, rpxI, csr_ui,
                           wprep + 2 * WSET_SH, h_item, (unsigned short*)nullptr, NI, NBIb,
                           xbI, (const unsigned short*)xbU, rpxU, csr_iu,
                           wprep + 3 * WSET_SH, h_user, (unsigned short*)nullptr, NU, 0);
    }
}

// Round 18
// 251.395 us; speedup vs baseline: 1.0568x; 1.0568x over previous
//
#include <hip/hip_runtime.h>

#define DD   32
#define BKT  128      // dsts per bucket (power of two)
#define BSH  7        // log2(BKT)
#define CAP  1536     // fixed slots per bucket (mean fill 1280, max ~1405)
#define PCH  4096     // edges per partition block
#define MAXB 2048     // padded bucket-count (>= nbkt)
#define WSET_SH 2112  // ushorts per weight set: 2048 B-frags + 64 (32 f32 bias)
#define CB   1024     // cast blocks inside k_mega

typedef __attribute__((ext_vector_type(8))) short short8v;   // 8 bf16 (4 VGPR)
typedef __attribute__((ext_vector_type(4))) float float4v;   // mfma C/D

// ---------- f32 -> bf16 (RNE) helpers ----------------------------------------
__device__ __forceinline__ unsigned bfr(float f) {
    unsigned u = __float_as_uint(f);
    return (u + 0x7fffu + ((u >> 16) & 1u)) >> 16;
}
__device__ __forceinline__ unsigned pk2(float a, float b) {
    return bfr(a) | (bfr(b) << 16);
}

// ---------- mega preamble: wprep | x->bf16 cast | bucket partition -----------
// Block roles by range: [0,4) wprep, [4,4+CB) cast, [4+CB, 4+CB+2*EB) part.
// All roles write disjoint buffers; part's cursors zeroed by preceding memset.
__global__ __launch_bounds__(256) void k_mega(
        const float* W0s, const float* W0n, const float* b0,
        const float* W1s, const float* W1n, const float* b1,
        const float* W2s, const float* W2n, const float* b2,
        const float* W3s, const float* W3n, const float* b3,
        unsigned short* __restrict__ wout,
        const float* __restrict__ xU, uint4* __restrict__ xbU, int n4U,
        const float* __restrict__ xI, uint4* __restrict__ xbI, int n4I,
        const int* __restrict__ srcA, const int* __restrict__ dstA,
        int* __restrict__ curA, int* __restrict__ stA,
        const int* __restrict__ srcB, const int* __restrict__ dstB,
        int* __restrict__ curB, int* __restrict__ stB,
        int E, int EB) {
    __shared__ int pk[PCH];
    __shared__ unsigned short bkl[PCH];
    __shared__ int hist[MAXB];
    __shared__ int basev[MAXB];
    __shared__ int gb[MAXB];
    __shared__ int red[256];
    int b = blockIdx.x;
    int t = threadIdx.x;
    if (b < 4) {                       // ---- weight prep: pack B fragments ----
        // B-frag for mfma_f32_16x16x32_bf16: lane l, reg i -> B[k][n],
        // n=(l&15)+nt*16, k=(l>>4)*8+i; B[k][n]=W[n][k]
        const float* Ws = (b == 0) ? W0s : (b == 1) ? W1s : (b == 2) ? W2s : W3s;
        const float* Wn = (b == 0) ? W0n : (b == 1) ? W1n : (b == 2) ? W2n : W3n;
        const float* bb = (b == 0) ? b0  : (b == 1) ? b1  : (b == 2) ? b2  : b3;
        unsigned short* o = wout + (size_t)b * WSET_SH;
        int pnt = t >> 6;              // 0:Ws-t0 1:Ws-t1 2:Wn-t0 3:Wn-t1
        int l   = t & 63;
        const float* W = (pnt < 2) ? Ws : Wn;
        int nt  = pnt & 1;
        int col = nt * 16 + (l & 15);
        int k0  = (l >> 4) * 8;
        unsigned short v[8];
#pragma unroll
        for (int i = 0; i < 8; ++i) v[i] = (unsigned short)bfr(W[col * DD + k0 + i]);
        uint4 pkv;
        pkv.x = v[0] | ((unsigned)v[1] << 16);
        pkv.y = v[2] | ((unsigned)v[3] << 16);
        pkv.z = v[4] | ((unsigned)v[5] << 16);
        pkv.w = v[6] | ((unsigned)v[7] << 16);
        *(uint4*)(o + (size_t)pnt * 512 + (size_t)l * 8) = pkv;
        if (t < DD) ((float*)(o + 2048))[t] = bb[t];
    } else if (b < 4 + CB) {           // ---- x -> bf16 cast ----
        int vb = b - 4;
        int total = n4U + n4I;
        for (int i = vb * 256 + t; i < total; i += CB * 256) {
            const float* s; uint4* dd; int j;
            if (i < n4U) { s = xU; dd = xbU; j = i; }
            else         { s = xI; dd = xbI; j = i - n4U; }
            float4 f0 = ((const float4*)s)[2 * j];
            float4 f1 = ((const float4*)s)[2 * j + 1];
            uint4 o;
            o.x = pk2(f0.x, f0.y); o.y = pk2(f0.z, f0.w);
            o.z = pk2(f1.x, f1.y); o.w = pk2(f1.z, f1.w);
            dd[j] = o;
        }
    } else {                           // ---- bucket partition ----
        int vb = b - 4 - CB;
        const int* src; const int* dst; int* cur; int* st; int bb;
        if (vb < EB) { src = srcA; dst = dstA; cur = curA; st = stA; bb = vb; }
        else         { src = srcB; dst = dstB; cur = curB; st = stB; bb = vb - EB; }
        int lo = bb * PCH;
        int cntE = E - lo; if (cntE > PCH) cntE = PCH;

        for (int i = t; i < MAXB; i += 256) hist[i] = 0;
        __syncthreads();
        for (int k = 0; k < PCH / 256; ++k) {
            int i = t + k * 256;
            if (i < cntE) atomicAdd(&hist[dst[lo + i] >> BSH], 1);
        }
        __syncthreads();
        {
            int base = t * 8;
            int loc[8]; int tot = 0;
            for (int j = 0; j < 8; ++j) { loc[j] = hist[base + j]; tot += loc[j]; }
            red[t] = tot;
            __syncthreads();
            for (int off = 1; off < 256; off <<= 1) {
                int v = (t >= off) ? red[t - off] : 0;
                __syncthreads();
                red[t] += v;
                __syncthreads();
            }
            int run = red[t] - tot;
            for (int j = 0; j < 8; ++j) { basev[base + j] = run; run += loc[j]; }
        }
        __syncthreads();
        for (int i = t; i < MAXB; i += 256) hist[i] = 0;
        __syncthreads();
        for (int k = 0; k < PCH / 256; ++k) {
            int i = t + k * 256;
            if (i < cntE) {
                int s = src[lo + i], d = dst[lo + i];
                int bk = d >> BSH;
                int pos = basev[bk] + atomicAdd(&hist[bk], 1);
                pk[pos]  = (s << BSH) | (d & (BKT - 1));
                bkl[pos] = (unsigned short)bk;
            }
        }
        __syncthreads();
        for (int i = t; i < MAXB; i += 256) { int c = hist[i]; gb[i] = c ? atomicAdd(&cur[i], c) : 0; }
        __syncthreads();
        for (int i = t; i < cntE; i += 256) {
            int bk = bkl[i];
            st[(size_t)bk * CAP + gb[bk] + (i - basev[bk])] = pk[i];
        }
    }
}

// ---------- in-bucket sort + 129-stride rowptr -------------------------------
__global__ __launch_bounds__(256) void k_bsort2(
        const int* __restrict__ curA, int* __restrict__ csrA, int* __restrict__ rpxA, int nbA,
        const int* __restrict__ curB, int* __restrict__ csrB, int* __restrict__ rpxB) {
    __shared__ int buf[CAP];
    __shared__ int hist[BKT];
    __shared__ int sc[BKT];
    __shared__ int cur[BKT];
    int b = blockIdx.x;
    const int* cc; int* csr; int* rpx; int bb;
    if (b < nbA) { cc = curA; csr = csrA; rpx = rpxA; bb = b; }
    else         { cc = curB; csr = csrB; rpx = rpxB; bb = b - nbA; }
    int t = threadIdx.x;
    int s0 = bb * CAP;
    int cnt = cc[bb];
    for (int i = t; i < cnt; i += 256) buf[i] = csr[s0 + i];
    if (t < BKT) hist[t] = 0;
    __syncthreads();
    for (int i = t; i < cnt; i += 256) atomicAdd(&hist[buf[i] & (BKT - 1)], 1);
    __syncthreads();
    int val = (t < BKT) ? hist[t] : 0;
    if (t < BKT) sc[t] = val;
    __syncthreads();
    for (int off = 1; off < BKT; off <<= 1) {
        int u = (t < BKT && t >= off) ? sc[t - off] : 0;
        __syncthreads();
        if (t < BKT) sc[t] += u;
        __syncthreads();
    }
    if (t < BKT) {
        int excl = sc[t] - val;
        cur[t] = excl;
        rpx[bb * (BKT + 1) + t] = s0 + excl;
    }
    if (t == BKT) rpx[bb * (BKT + 1) + BKT] = s0 + cnt;
    __syncthreads();
    for (int i = t; i < cnt; i += 256) {
        int p = buf[i];
        int pos = atomicAdd(&cur[p & (BKT - 1)], 1);
        csr[s0 + pos] = p >> BSH;
    }
}

// ---------- h f32 -> bf16 cast (fallback path only) ---------------------------
__global__ __launch_bounds__(256) void k_cast2(
        const float* __restrict__ sA, uint4* __restrict__ dA, int nA,
        const float* __restrict__ sB, uint4* __restrict__ dB, int nB) {
    int total = nA + nB;
    for (int i = blockIdx.x * 256 + threadIdx.x; i < total; i += gridDim.x * 256) {
        const float* s; uint4* dd; int j;
        if (i < nA) { s = sA; dd = dA; j = i; }
        else        { s = sB; dd = dB; j = i - nA; }
        float4 f0 = ((const float4*)s)[2 * j];
        float4 f1 = ((const float4*)s)[2 * j + 1];
        uint4 o;
        o.x = pk2(f0.x, f0.y); o.y = pk2(f0.z, f0.w);
        o.z = pk2(f1.x, f1.y); o.w = pk2(f1.z, f1.w);
        dd[j] = o;
    }
}

// ---------- quad reduce via DPP (xor1 then xor2, pure VALU) -------------------
__device__ __forceinline__ float qred(float x) {
    x += __int_as_float(__builtin_amdgcn_update_dpp(
            0, __float_as_int(x), 0xB1, 0xF, 0xF, true));
    x += __int_as_float(__builtin_amdgcn_update_dpp(
            0, __float_as_int(x), 0x4E, 0xF, 0xF, true));
    return x;
}

// ---------- fused: gather(bf16) + MFMA transform ------------------------------
__device__ __forceinline__ void fused_body(
        const uint4* __restrict__ gsrc, const unsigned short* __restrict__ xdb,
        const int* __restrict__ rpx, const int* __restrict__ csr_src,
        const unsigned short* __restrict__ wset,
        float* __restrict__ out, unsigned short* __restrict__ outbf,
        int n, int do_relu, int bb) {
    __shared__ unsigned short xm[64][72];
    int tid = threadIdx.x;
    int grp = tid >> 4;
    int ln  = tid & 15;
    int el  = ln & 3;
    int q   = ln >> 2;
    int l64 = tid & 63;
    int w   = tid >> 6;

    const short8v* wb = (const short8v*)wset;
    short8v Bs0 = wb[0 * 64 + l64];
    short8v Bs1 = wb[1 * 64 + l64];
    short8v Bn0 = wb[2 * 64 + l64];
    short8v Bn1 = wb[3 * 64 + l64];
    const float* bias = (const float*)(wset + 2048);
    float bv0 = bias[l64 & 15];
    float bv1 = bias[16 + (l64 & 15)];

#pragma unroll 2
    for (int nn = 0; nn < 4; ++nn) {
        int nl = grp * 4 + nn;
        int v  = bb * 64 + nl;
        if (v < n) {
            ((unsigned*)xm[nl])[ln] = ((const unsigned*)xdb)[(unsigned)v * 16u + ln];
            int rb = (v >> BSH) * (BKT + 1) + (v & (BKT - 1));
            int rs = rpx[rb], re = rpx[rb + 1];
            float a0 = 0.f, a1 = 0.f, a2 = 0.f, a3 = 0.f;
            float a4 = 0.f, a5 = 0.f, a6 = 0.f, a7 = 0.f;
            for (int j0 = rs; j0 < re; j0 += 16) {
                int nj = re - j0; if (nj > 16) nj = 16;
                int myi = (ln < nj) ? csr_src[j0 + ln] : 0;
                for (int c0 = 0; c0 < nj; c0 += 8) {
                    int jj0 = c0 + el;
                    int jj1 = c0 + 4 + el;
                    int s0 = __shfl(myi, jj0, 16);
                    int s1 = __shfl(myi, jj1, 16);
                    if (jj0 < nj) {
                        uint4 w4 = gsrc[(unsigned)s0 * 4u + q];
                        a0 += __uint_as_float(w4.x << 16); a1 += __uint_as_float(w4.x & 0xFFFF0000u);
                        a2 += __uint_as_float(w4.y << 16); a3 += __uint_as_float(w4.y & 0xFFFF0000u);
                        a4 += __uint_as_float(w4.z << 16); a5 += __uint_as_float(w4.z & 0xFFFF0000u);
                        a6 += __uint_as_float(w4.w << 16); a7 += __uint_as_float(w4.w & 0xFFFF0000u);
                    }
                    if (jj1 < nj) {
                        uint4 w4 = gsrc[(unsigned)s1 * 4u + q];
                        a0 += __uint_as_float(w4.x << 16); a1 += __uint_as_float(w4.x & 0xFFFF0000u);
                        a2 += __uint_as_float(w4.y << 16); a3 += __uint_as_float(w4.y & 0xFFFF0000u);
                        a4 += __uint_as_float(w4.z << 16); a5 += __uint_as_float(w4.z & 0xFFFF0000u);
                        a6 += __uint_as_float(w4.w << 16); a7 += __uint_as_float(w4.w & 0xFFFF0000u);
                    }
                }
            }
            a0 = qred(a0); a1 = qred(a1); a2 = qred(a2); a3 = qred(a3);
            a4 = qred(a4); a5 = qred(a5); a6 = qred(a6); a7 = qred(a7);
            float rinv = 1.0f / fmaxf((float)(re - rs), 1.0f);
            if (el == 0) {
                uint4 m4;
                m4.x = pk2(a0 * rinv, a1 * rinv);
                m4.y = pk2(a2 * rinv, a3 * rinv);
                m4.z = pk2(a4 * rinv, a5 * rinv);
                m4.w = pk2(a6 * rinv, a7 * rinv);
                *(uint4*)(&xm[nl][32 + q * 8]) = m4;
            }
        } else {
            ((unsigned*)xm[nl])[ln] = 0;
            if (el == 0) {
                uint4 z; z.x = z.y = z.z = z.w = 0;
                *(uint4*)(&xm[nl][32 + q * 8]) = z;
            }
        }
    }
    __syncthreads();

    int row16 = l64 & 15;
    int kg    = l64 >> 4;
    int nrow  = w * 16 + row16;
    short8v Ax = *(const short8v*)(&xm[nrow][kg * 8]);
    short8v Am = *(const short8v*)(&xm[nrow][32 + kg * 8]);
    float4v c0 = {0.f, 0.f, 0.f, 0.f};
    float4v c1 = {0.f, 0.f, 0.f, 0.f};
    c0 = __builtin_amdgcn_mfma_f32_16x16x32_bf16(Ax, Bs0, c0, 0, 0, 0);
    c0 = __builtin_amdgcn_mfma_f32_16x16x32_bf16(Am, Bn0, c0, 0, 0, 0);
    c1 = __builtin_amdgcn_mfma_f32_16x16x32_bf16(Ax, Bs1, c1, 0, 0, 0);
    c1 = __builtin_amdgcn_mfma_f32_16x16x32_bf16(Am, Bn1, c1, 0, 0, 0);
    int ccol  = l64 & 15;
    int crow0 = (l64 >> 4) * 4;
#pragma unroll
    for (int j = 0; j < 4; ++j) {
        int r = w * 16 + crow0 + j;
        int v = bb * 64 + r;
        if (v < n) {
            float s0v = c0[j] + bv0;
            float s1v = c1[j] + bv1;
            if (do_relu) { s0v = fmaxf(s0v, 0.f); s1v = fmaxf(s1v, 0.f); }
            if (out) {
                out[(unsigned)v * DD + ccol]      = s0v;
                out[(unsigned)v * DD + 16 + ccol] = s1v;
            }
            if (outbf) {
                outbf[(unsigned)v * DD + ccol]      = (unsigned short)bfr(s0v);
                outbf[(unsigned)v * DD + 16 + ccol] = (unsigned short)bfr(s1v);
            }
        }
    }
}

__global__ __launch_bounds__(256) void k_fused2(
        const uint4* gA, const unsigned short* xdA, const int* rpA, const int* csrA,
        const unsigned short* wsetA, float* outA, unsigned short* obfA, int nA, int blocksA,
        const uint4* gB, const unsigned short* xdB, const int* rpB, const int* csrB,
        const unsigned short* wsetB, float* outB, unsigned short* obfB, int nB, int do_relu) {
    int b = blockIdx.x;
    bool A = b < blocksA;
    fused_body(A ? gA : gB, A ? xdA : xdB, A ? rpA : rpB, A ? csrA : csrB,
               A ? wsetA : wsetB, A ? outA : outB, A ? obfA : obfB,
               A ? nA : nB, do_relu, A ? b : b - blocksA);
}

extern "C" void kernel_launch(void* const* d_in, const int* in_sizes, int n_in,
                              void* d_out, int out_size, void* d_ws, size_t ws_size,
                              hipStream_t stream) {
    const float* x_user = (const float*)d_in[0];
    const float* x_item = (const float*)d_in[1];
    const int*   ui_src = (const int*)d_in[2];
    const int*   ui_dst = (const int*)d_in[3];
    const int*   iu_src = (const int*)d_in[4];
    const int*   iu_dst = (const int*)d_in[5];
    const float* Ws_ui1 = (const float*)d_in[6];
    const float* Wn_ui1 = (const float*)d_in[7];
    const float* Ws_iu1 = (const float*)d_in[8];
    const float* Wn_iu1 = (const float*)d_in[9];
    const float* Ws_ui2 = (const float*)d_in[10];
    const float* Wn_ui2 = (const float*)d_in[11];
    const float* Ws_iu2 = (const float*)d_in[12];
    const float* Wn_iu2 = (const float*)d_in[13];
    const float* b_ui1  = (const float*)d_in[14];
    const float* b_iu1  = (const float*)d_in[15];
    const float* b_ui2  = (const float*)d_in[16];
    const float* b_iu2  = (const float*)d_in[17];

    int NU = in_sizes[0] / DD;
    int NI = in_sizes[1] / DD;
    int E  = in_sizes[2];
    int NBI = (NI + BKT - 1) >> BSH;
    int NBU = (NU + BKT - 1) >> BSH;

    // ---- workspace sizing ----
    size_t base_need = (size_t)(NU + NI) * 64
                     + (size_t)(NBI + NBU) * CAP * 4
                     + (size_t)(NBI + NBU) * (BKT + 1) * 4
                     + (size_t)4 * WSET_SH * 2
                     + (size_t)2 * MAXB * 4 + 512;
    size_t hb_extra = (size_t)(NU + NI) * 64;
    bool path1 = (ws_size >= base_need + hb_extra);

    char* wp = (char*)d_ws;
    uint4* xbU = (uint4*)wp;     wp += (size_t)NU * 64;
    uint4* xbI = (uint4*)wp;     wp += (size_t)NI * 64;
    uint4* hbU = xbU;
    uint4* hbI = xbI;
    if (path1) {
        hbU = (uint4*)wp;        wp += (size_t)NU * 64;
        hbI = (uint4*)wp;        wp += (size_t)NI * 64;
    }
    int* csr_ui = (int*)wp;      wp += (size_t)NBI * CAP * 4;
    int* csr_iu = (int*)wp;      wp += (size_t)NBU * CAP * 4;
    int* rpxI   = (int*)wp;      wp += (size_t)NBI * (BKT + 1) * 4;
    int* rpxU   = (int*)wp;      wp += (size_t)NBU * (BKT + 1) * 4;
    wp = (char*)(((size_t)wp + 15) & ~(size_t)15);
    unsigned short* wprep = (unsigned short*)wp;  wp += (size_t)4 * WSET_SH * 2;
    int* curI = (int*)wp;        wp += (size_t)MAXB * 4;
    int* curU = (int*)wp;

    float* h_user = (float*)d_out;
    float* h_item = h_user + (size_t)NU * DD;

    int EB = (E + PCH - 1) / PCH;

    // ---- zero cursors, then mega preamble (wprep | cast | partition) ----
    (void)hipMemsetAsync(curI, 0, (size_t)2 * MAXB * sizeof(int), stream);
    hipLaunchKernelGGL(k_mega, dim3(4 + CB + 2 * EB), dim3(256), 0, stream,
                       Ws_ui1, Wn_ui1, b_ui1, Ws_iu1, Wn_iu1, b_iu1,
                       Ws_ui2, Wn_ui2, b_ui2, Ws_iu2, Wn_iu2, b_iu2, wprep,
                       x_user, xbU, NU * 4, x_item, xbI, NI * 4,
                       ui_src, ui_dst, curI, csr_ui,
                       iu_src, iu_dst, curU, csr_iu, E, EB);

    // ---- in-bucket sort + rowptr ----
    hipLaunchKernelGGL(k_bsort2, dim3(NBI + NBU), dim3(256), 0, stream,
                       curI, csr_ui, rpxI, NBI,
                       curU, csr_iu, rpxU);

    int NBIb = (NI + 63) / 64, NBUb = (NU + 63) / 64;

    if (path1) {
        // L1: gather x-bf16, write h bf16 only
        hipLaunchKernelGGL(k_fused2, dim3(NBIb + NBUb), dim3(256), 0, stream,
                           xbU, (const unsigned short*)xbI, rpxI, csr_ui,
                           wprep + 0 * WSET_SH, (float*)nullptr, (unsigned short*)hbI, NI, NBIb,
                           xbI, (const unsigned short*)xbU, rpxU, csr_iu,
                           wprep + 1 * WSET_SH, (float*)nullptr, (unsigned short*)hbU, NU, 1);
        // L2: gather h-bf16, write f32 outputs to d_out
        hipLaunchKernelGGL(k_fused2, dim3(NBIb + NBUb), dim3(256), 0, stream,
                           hbU, (const unsigned short*)hbI, rpxI, csr_ui,
                           wprep + 2 * WSET_SH, h_item, (unsigned short*)nullptr, NI, NBIb,
                           hbI, (const unsigned short*)hbU, rpxU, csr_iu,
                           wprep + 3 * WSET_SH, h_user, (unsigned short*)nullptr, NU, 0);
    } else {
        hipLaunchKernelGGL(k_fused2, dim3(NBIb + NBUb), dim3(256), 0, stream,
                           xbU, (const unsigned short*)xbI, rpxI, csr_ui,
                           wprep + 0 * WSET_SH, h_item, (unsigned short*)nullptr, NI, NBIb,
                           xbI, (const unsigned short*)xbU, rpxU, csr_iu,
                           wprep + 1 * WSET_SH, h_user, (unsigned short*)nullptr, NU, 1);
        hipLaunchKernelGGL(k_cast2, dim3(1024), dim3(256), 0, stream,
                           h_user, xbU, NU * 4, h_item, xbI, NI * 4);
        hipLaunchKernelGGL(k_fused2, dim3(NBIb + NBUb), dim3(256), 0, stream,
                           xbU, (const unsigned short*)xbI, rpxI, csr_ui,
                           wprep + 2 * WSET_SH, h_item, (unsigned short*)nullptr, NI, NBIb,
                           xbI, (const unsigned short*)xbU, rpxU, csr_iu,
                           wprep + 3 * WSET_SH, h_user, (unsigned short*)nullptr, NU, 0);
    }
}